// Round 1
// 553.381 us; speedup vs baseline: 1.2934x; 1.2934x over previous
//
#include <hip/hip_runtime.h>

// ---------------- types / helpers ----------------
typedef short v8s __attribute__((ext_vector_type(8)));
typedef float v4f __attribute__((ext_vector_type(4)));

#define MFMA16(a, b, c) __builtin_amdgcn_mfma_f32_16x16x32_bf16(a, b, c, 0, 0, 0)

__device__ __forceinline__ unsigned short f2b(float f) {
  union { float f; unsigned int i; } v;
  v.f = f;
  unsigned int x = v.i;
  return (unsigned short)((x + 0x7fffu + ((x >> 16) & 1u)) >> 16);
}
// load 16 bytes (8 bf16) via two 8B LDS reads (rows may be only 8B-aligned)
__device__ __forceinline__ v8s ld16u(const unsigned short* p) {
  union { v8s v; ushort4 h[2]; } u;
  u.h[0] = *(const ushort4*)(p);
  u.h[1] = *(const ushort4*)(p + 4);
  return u.v;
}
// stage a 128x128 fp32 global tile into swizzled bf16 LDS (16B granules)
__device__ __forceinline__ void stage128(const float* __restrict__ src,
                                         unsigned short* __restrict__ xs, int tid) {
  for (int it = 0; it < 8; ++it) {
    int gl = tid + 256 * it;           // 0..2047
    int row = gl >> 4, g = gl & 15;    // row 0..127, 16B-granule 0..15
    const float4* s = (const float4*)(src + row * 128 + g * 8);
    float4 a = s[0], b = s[1];
    union { int4 v; unsigned short u[8]; } pk;
    pk.u[0] = f2b(a.x); pk.u[1] = f2b(a.y); pk.u[2] = f2b(a.z); pk.u[3] = f2b(a.w);
    pk.u[4] = f2b(b.x); pk.u[5] = f2b(b.y); pk.u[6] = f2b(b.z); pk.u[7] = f2b(b.w);
    *(int4*)(xs + row * 128 + ((g ^ (row & 15)) << 3)) = pk.v;
  }
}

#define SCALE 0.17677669529663687f

// workspace layout (bytes):
//   [0, 16 MiB)                  msumT[256][128][128]  fp32 (mask+sp, TRANSPOSED [m][n])
//   [16 MiB, +256 KiB)           rpbT[4][128][128]     fp32 (btab[rpi], TRANSPOSED [m][n])
//   [17039360, +96 KiB)          wqh: w_qkv bf16 row-major 384x128
//   [17137664, +32 KiB)          wph: w_proj bf16 row-major 128x128
#define WS_RPB 16777216
#define WS_WQH 17039360
#define WS_WPH 17137664

// ---------------- K0a: weight fp32 -> bf16 (65536 elems, grid 256) ----------
__global__ __launch_bounds__(256)
void conv_w(const float* __restrict__ wq, const float* __restrict__ wp,
            unsigned short* __restrict__ wqh, unsigned short* __restrict__ wph) {
  int i = blockIdx.x * 256 + threadIdx.x;
  if (i < 384 * 128) wqh[i] = f2b(wq[i]);
  else wph[i - 384 * 128] = f2b(wp[i - 384 * 128]);
}

// ---------------- K0b: bias precompute (grid 256 = wgrp) --------------------
// msumT[wgrp][m][n] = mask[wgrp][n][m] + sp[wgrp][n][m]   (LDS transpose)
// rpbT flat elem e = h*16384 + m*128 + n = btab[rpi[n][m]*4 + h]
__global__ __launch_bounds__(256)
void build_bias(const float* __restrict__ mask, const float* __restrict__ sp,
                const int* __restrict__ rpi, const float* __restrict__ btab,
                float* __restrict__ msumT, float* __restrict__ rpbT) {
  __shared__ float t[64][132];
  const int wgrp = blockIdx.x, tid = threadIdx.x;
  const float* mk = mask + (size_t)wgrp * 16384;
  const float* sk = sp + (size_t)wgrp * 16384;
  float* ot = msumT + (size_t)wgrp * 16384;
  for (int c = 0; c < 2; ++c) {
    for (int it = 0; it < 8; ++it) {
      int idx = tid + 256 * it;         // 0..2047 float4s of a 64x128 slab
      int nl = idx >> 5, f = idx & 31;
      float4 a = *(const float4*)(mk + (c * 64 + nl) * 128 + f * 4);
      float4 b = *(const float4*)(sk + (c * 64 + nl) * 128 + f * 4);
      float4 s;
      s.x = a.x + b.x; s.y = a.y + b.y; s.z = a.z + b.z; s.w = a.w + b.w;
      *(float4*)(&t[nl][f * 4]) = s;
    }
    __syncthreads();
    for (int it = 0; it < 8; ++it) {
      int idx = tid + 256 * it;
      int m = idx >> 4, j = idx & 15;
      float4 o;
      o.x = t[j * 4 + 0][m]; o.y = t[j * 4 + 1][m];
      o.z = t[j * 4 + 2][m]; o.w = t[j * 4 + 3][m];
      *(float4*)(ot + m * 128 + c * 64 + j * 4) = o;
    }
    __syncthreads();
  }
  int e = wgrp * 256 + tid;             // 0..65535 over [h][m][n]
  int rem = e & 16383;
  int h = e >> 14, m = rem >> 7, n = rem & 127;
  rpbT[e] = btab[rpi[n * 128 + m] * 4 + h];
}

// ---------------- K1: fused qkv + attention per (b, h) ----------------
// 3 blocks/CU now: Q stays in registers (intra-wave shuffle), LDS = 51456 B.
__global__ __launch_bounds__(256, 3)
void attn_kernel(const float* __restrict__ xg,
                 const unsigned short* __restrict__ wqh,
                 const float* __restrict__ bq,
                 const float* __restrict__ msumT,
                 const float* __restrict__ rpbT,
                 float* __restrict__ o_ws) {
  // LDS: [0,33792) P (128x132) aliased with X (128x128 swizzled, 32KB)
  //      [33792,43008) K (128x36)   [43008,51456) V^T (32x132)
  __shared__ alignas(16) unsigned char smem[51456];
  unsigned short* ps  = (unsigned short*)smem;
  unsigned short* xs  = (unsigned short*)smem;
  unsigned short* kss = (unsigned short*)(smem + 33792);
  unsigned short* vs  = (unsigned short*)(smem + 43008);

  const int tid = threadIdx.x;
  const int wv = tid >> 6;
  const int lane = tid & 63;
  const int qd = lane >> 4;   // quarter 0..3
  const int t16 = lane & 15;

  const int idx = blockIdx.x;
  const int wgrp = idx >> 5;          // 0..255 : mask index
  const int rem = idx & 31;
  const int h = rem >> 3;             // head
  const int b = (rem & 7) * 256 + wgrp;  // window (b % 256 == wgrp)

  // ---- stage x[b] (128x128 fp32 -> bf16 LDS, XOR swizzle) ----
  stage128(xg + (size_t)b * 16384, xs, tid);
  __syncthreads();

  // ---- phase 1: qkv slices for this head ----
  v8s bx[2][4];
  for (int nt = 0; nt < 2; ++nt)
    for (int ks = 0; ks < 4; ++ks) {
      int n = 32 * wv + nt * 16 + t16;
      int g = ks * 4 + qd;
      bx[nt][ks] = *(const v8s*)(xs + n * 128 + ((g ^ (n & 15)) << 3));
    }

  // q,k via out^T = W @ X^T : rows j (0..63: q then k), cols n (wave strip 32)
  v4f accqk[4][2];
  for (int jt = 0; jt < 4; ++jt)
    for (int nt = 0; nt < 2; ++nt) accqk[jt][nt] = v4f{0.f, 0.f, 0.f, 0.f};
  for (int jt = 0; jt < 4; ++jt) {
    int wbase = (jt < 2) ? (h * 32 + jt * 16) : (128 + h * 32 + (jt - 2) * 16);
    for (int ks = 0; ks < 4; ++ks) {
      v8s a = *(const v8s*)(wqh + (wbase + t16) * 128 + ks * 32 + 8 * qd);
      for (int nt = 0; nt < 2; ++nt)
        accqk[jt][nt] = MFMA16(a, bx[nt][ks], accqk[jt][nt]);
    }
  }
  // v via out = X @ Wv^T : rows n (strip 32), cols d (32)
  v4f accv[2][2];
  for (int rt = 0; rt < 2; ++rt)
    for (int ct = 0; ct < 2; ++ct) accv[rt][ct] = v4f{0.f, 0.f, 0.f, 0.f};
  for (int ct = 0; ct < 2; ++ct)
    for (int ks = 0; ks < 4; ++ks) {
      v8s bw = *(const v8s*)(wqh + (256 + h * 32 + ct * 16 + t16) * 128 + ks * 32 + 8 * qd);
      for (int rt = 0; rt < 2; ++rt)
        accv[rt][ct] = MFMA16(bx[rt][ks], bw, accv[rt][ct]);
    }

  // epilogue k (jt=2,3): packed 8B LDS stores
  for (int jt = 2; jt < 4; ++jt)
    for (int nt = 0; nt < 2; ++nt) {
      int n = 32 * wv + nt * 16 + t16;
      ushort4 pk;
      float v0 = accqk[jt][nt][0] + bq[128 + h * 32 + (jt - 2) * 16 + 4 * qd + 0];
      float v1 = accqk[jt][nt][1] + bq[128 + h * 32 + (jt - 2) * 16 + 4 * qd + 1];
      float v2 = accqk[jt][nt][2] + bq[128 + h * 32 + (jt - 2) * 16 + 4 * qd + 2];
      float v3 = accqk[jt][nt][3] + bq[128 + h * 32 + (jt - 2) * 16 + 4 * qd + 3];
      pk.x = f2b(v0); pk.y = f2b(v1); pk.z = f2b(v2); pk.w = f2b(v3);
      *(ushort4*)(kss + n * 36 + (jt - 2) * 16 + 4 * qd) = pk;
    }
  // epilogue v: store transposed V^T[d][n], 4 consecutive n per reg -> 8B stores
  for (int ct = 0; ct < 2; ++ct) {
    int d = ct * 16 + t16;
    float bv = bq[256 + h * 32 + d];
    for (int rt = 0; rt < 2; ++rt) {
      ushort4 pk;
      pk.x = f2b(accv[rt][ct][0] + bv);
      pk.y = f2b(accv[rt][ct][1] + bv);
      pk.z = f2b(accv[rt][ct][2] + bv);
      pk.w = f2b(accv[rt][ct][3] + bv);
      *(ushort4*)(vs + d * 132 + 32 * wv + rt * 16 + 4 * qd) = pk;
    }
  }

  // ---- Q: pack bf16 dword pairs, redistribute in-register (no LDS) ----
  // source thread (qd,t16) holds Q^T[d = jt*16+4qd+r][n = 32wv+nt*16+t16].
  // target thread (qd,t16) needs aq[rt] = Q[n = 32wv+rt*16+t16][8qd..8qd+7]:
  //   dwords 0,1 from lane 32*(qd&1)+t16 (jt=qd>>1, dw 0/1),
  //   dwords 2,3 from lane 32*(qd&1)+16+t16.
  unsigned int qpk[2][2][2];  // [jt][nt][dw]
  for (int jt = 0; jt < 2; ++jt)
    for (int nt = 0; nt < 2; ++nt) {
      float vv[4];
      for (int r = 0; r < 4; ++r)
        vv[r] = (accqk[jt][nt][r] + bq[h * 32 + jt * 16 + 4 * qd + r]) * SCALE;
      qpk[jt][nt][0] = (unsigned int)f2b(vv[0]) | ((unsigned int)f2b(vv[1]) << 16);
      qpk[jt][nt][1] = (unsigned int)f2b(vv[2]) | ((unsigned int)f2b(vv[3]) << 16);
    }
  const int srcA = ((qd & 1) << 5) + t16;
  const bool hiq = qd >= 2;
  v8s aq[2];
  for (int rt = 0; rt < 2; ++rt) {
    union { v8s v; unsigned int d[4]; } u;
    unsigned int a0 = __shfl((int)qpk[0][rt][0], srcA, 64);
    unsigned int b0 = __shfl((int)qpk[1][rt][0], srcA, 64);
    unsigned int a1 = __shfl((int)qpk[0][rt][1], srcA, 64);
    unsigned int b1 = __shfl((int)qpk[1][rt][1], srcA, 64);
    unsigned int a2 = __shfl((int)qpk[0][rt][0], srcA + 16, 64);
    unsigned int b2 = __shfl((int)qpk[1][rt][0], srcA + 16, 64);
    unsigned int a3 = __shfl((int)qpk[0][rt][1], srcA + 16, 64);
    unsigned int b3 = __shfl((int)qpk[1][rt][1], srcA + 16, 64);
    u.d[0] = hiq ? b0 : a0;
    u.d[1] = hiq ? b1 : a1;
    u.d[2] = hiq ? b2 : a2;
    u.d[3] = hiq ? b3 : a3;
    aq[rt] = u.v;
  }
  __syncthreads();

  // ---- phase 2: S = Q K^T (+ precomputed bias), softmax -> P (bf16) ----
  v4f sa[2][8];
  const v4f zero4 = {0.f, 0.f, 0.f, 0.f};
  for (int ct = 0; ct < 8; ++ct) {
    int key = ct * 16 + t16;
    v8s bk = ld16u(kss + key * 36 + 8 * qd);
    for (int rt = 0; rt < 2; ++rt)
      sa[rt][ct] = MFMA16(aq[rt], bk, zero4);
  }
  // bias: msumT[wgrp][m][n] + rpbT[h][m][n], float4 along n (matches r-dim)
  {
    const float* mt = msumT + (size_t)wgrp * 16384;
    const float* rb = rpbT + (size_t)h * 16384;
    for (int ct = 0; ct < 8; ++ct) {
      int m = ct * 16 + t16;
      const float* pm = mt + m * 128;
      const float* pr = rb + m * 128;
      for (int rt = 0; rt < 2; ++rt) {
        int n0 = 32 * wv + rt * 16 + 4 * qd;
        float4 b1 = *(const float4*)(pm + n0);
        float4 b2 = *(const float4*)(pr + n0);
        sa[rt][ct][0] += b1.x + b2.x;
        sa[rt][ct][1] += b1.y + b2.y;
        sa[rt][ct][2] += b1.z + b2.z;
        sa[rt][ct][3] += b1.w + b2.w;
      }
    }
  }
  float pmax[2][4], pinv[2][4];
  for (int rt = 0; rt < 2; ++rt)
    for (int r = 0; r < 4; ++r) {
      float m0 = sa[rt][0][r];
      for (int ct = 1; ct < 8; ++ct) m0 = fmaxf(m0, sa[rt][ct][r]);
      m0 = fmaxf(m0, __shfl_xor(m0, 1));
      m0 = fmaxf(m0, __shfl_xor(m0, 2));
      m0 = fmaxf(m0, __shfl_xor(m0, 4));
      m0 = fmaxf(m0, __shfl_xor(m0, 8));
      pmax[rt][r] = m0;
    }
  for (int rt = 0; rt < 2; ++rt)
    for (int ct = 0; ct < 8; ++ct)
      for (int r = 0; r < 4; ++r)
        sa[rt][ct][r] = __expf(sa[rt][ct][r] - pmax[rt][r]);
  for (int rt = 0; rt < 2; ++rt)
    for (int r = 0; r < 4; ++r) {
      float s0 = 0.f;
      for (int ct = 0; ct < 8; ++ct) s0 += sa[rt][ct][r];
      s0 += __shfl_xor(s0, 1);
      s0 += __shfl_xor(s0, 2);
      s0 += __shfl_xor(s0, 4);
      s0 += __shfl_xor(s0, 8);
      pinv[rt][r] = 1.0f / s0;
    }
  // write normalized P (bf16)
  for (int rt = 0; rt < 2; ++rt)
    for (int r = 0; r < 4; ++r) {
      int n = 32 * wv + rt * 16 + 4 * qd + r;
      for (int ct = 0; ct < 8; ++ct)
        ps[n * 132 + ct * 16 + t16] = f2b(sa[rt][ct][r] * pinv[rt][r]);
    }
  __syncthreads();

  // ---- phase 3: O^T = V^T P^T ; write O[b][n][h*32+d] (float4 stores) ----
  v8s av[2][4];
  for (int rt = 0; rt < 2; ++rt)
    for (int ks = 0; ks < 4; ++ks) {
      int d = rt * 16 + t16;
      av[rt][ks] = ld16u(vs + d * 132 + ks * 32 + 8 * qd);
    }
  v4f oa[2][2];
  for (int rt = 0; rt < 2; ++rt)
    for (int ct = 0; ct < 2; ++ct) oa[rt][ct] = v4f{0.f, 0.f, 0.f, 0.f};
  for (int ct = 0; ct < 2; ++ct) {
    int n = 32 * wv + ct * 16 + t16;
    for (int ks = 0; ks < 4; ++ks) {
      v8s bp = ld16u(ps + n * 132 + ks * 32 + 8 * qd);
      for (int rt = 0; rt < 2; ++rt)
        oa[rt][ct] = MFMA16(av[rt][ks], bp, oa[rt][ct]);
    }
  }
  for (int rt = 0; rt < 2; ++rt)
    for (int ct = 0; ct < 2; ++ct) {
      int n = 32 * wv + ct * 16 + t16;
      int cbase = h * 32 + rt * 16 + 4 * qd;
      float4 pk;
      pk.x = oa[rt][ct][0];
      pk.y = oa[rt][ct][1];
      pk.z = oa[rt][ct][2];
      pk.w = oa[rt][ct][3];
      *(float4*)(o_ws + ((size_t)(b * 128 + n)) * 128 + cbase) = pk;
    }
}

// ---------------- K2: out = O @ w_proj^T + b_proj (IN PLACE on d_out) -------
// computed as out^T = Wp @ O^T so C-fragments give 4 consecutive channels
__global__ __launch_bounds__(256, 3)
void proj_kernel(const unsigned short* __restrict__ wph,
                 const float* __restrict__ bpj,
                 float* __restrict__ out) {
  __shared__ alignas(16) unsigned short os[128 * 128];  // bf16 O tile, swizzled
  const int tid = threadIdx.x;
  const int wv = tid >> 6;
  const int lane = tid & 63;
  const int qd = lane >> 4;
  const int t16 = lane & 15;
  const size_t row0 = (size_t)blockIdx.x * 128;

  stage128(out + row0 * 128, os, tid);   // all reads of out rows before barrier
  __syncthreads();

  // B-frags: token rows n from LDS (k = input channel)
  v8s bo[2][4];
  for (int ct = 0; ct < 2; ++ct)
    for (int ks = 0; ks < 4; ++ks) {
      int n = 32 * wv + ct * 16 + t16;
      int g = ks * 4 + qd;
      bo[ct][ks] = *(const v8s*)(os + n * 128 + ((g ^ (n & 15)) << 3));
    }
  v4f acc[8][2];
  for (int rt = 0; rt < 8; ++rt)
    for (int ct = 0; ct < 2; ++ct) acc[rt][ct] = v4f{0.f, 0.f, 0.f, 0.f};
  for (int rt = 0; rt < 8; ++rt)
    for (int ks = 0; ks < 4; ++ks) {
      v8s a = *(const v8s*)(wph + (rt * 16 + t16) * 128 + ks * 32 + 8 * qd);
      for (int ct = 0; ct < 2; ++ct)
        acc[rt][ct] = MFMA16(a, bo[ct][ks], acc[rt][ct]);
    }
  for (int rt = 0; rt < 8; ++rt) {
    float4 bj = *(const float4*)(bpj + rt * 16 + 4 * qd);
    for (int ct = 0; ct < 2; ++ct) {
      int n = 32 * wv + ct * 16 + t16;
      float4 pk;
      pk.x = acc[rt][ct][0] + bj.x;
      pk.y = acc[rt][ct][1] + bj.y;
      pk.z = acc[rt][ct][2] + bj.z;
      pk.w = acc[rt][ct][3] + bj.w;
      *(float4*)(out + (row0 + n) * 128 + rt * 16 + 4 * qd) = pk;
    }
  }
}

// ---------------- launch ----------------
extern "C" void kernel_launch(void* const* d_in, const int* in_sizes, int n_in,
                              void* d_out, int out_size, void* d_ws, size_t ws_size,
                              hipStream_t stream) {
  (void)in_sizes; (void)n_in; (void)out_size; (void)ws_size;
  const float* xg   = (const float*)d_in[0];
  const int*   rpi  = (const int*)d_in[1];
  const float* mask = (const float*)d_in[2];
  const float* sp   = (const float*)d_in[3];
  const float* wq   = (const float*)d_in[4];
  const float* bq   = (const float*)d_in[5];
  const float* btab = (const float*)d_in[6];
  const float* wp   = (const float*)d_in[7];
  const float* bpj  = (const float*)d_in[8];
  float* out = (float*)d_out;

  float* msumT = (float*)d_ws;                                   // 16 MiB
  float* rpbT  = (float*)((char*)d_ws + WS_RPB);                 // 256 KiB
  unsigned short* wqh = (unsigned short*)((char*)d_ws + WS_WQH); // 96 KiB
  unsigned short* wph = (unsigned short*)((char*)d_ws + WS_WPH); // 32 KiB

  conv_w<<<256, 256, 0, stream>>>(wq, wp, wqh, wph);
  build_bias<<<256, 256, 0, stream>>>(mask, sp, rpi, btab, msumT, rpbT);
  // O intermediate lives in d_out; proj projects in place.
  attn_kernel<<<8192, 256, 0, stream>>>(xg, wqh, bq, msumT, rpbT, out);
  proj_kernel<<<2048, 256, 0, stream>>>(wph, bpj, out);
}

// Round 2
// 553.019 us; speedup vs baseline: 1.2942x; 1.0007x over previous
//
#include <hip/hip_runtime.h>

// ---------------- types / helpers ----------------
typedef short v8s __attribute__((ext_vector_type(8)));
typedef float v4f __attribute__((ext_vector_type(4)));

#define MFMA16(a, b, c) __builtin_amdgcn_mfma_f32_16x16x32_bf16(a, b, c, 0, 0, 0)

__device__ __forceinline__ unsigned short f2b(float f) {
  union { float f; unsigned int i; } v;
  v.f = f;
  unsigned int x = v.i;
  return (unsigned short)((x + 0x7fffu + ((x >> 16) & 1u)) >> 16);
}
// load 8 consecutive fp32 from global, convert to bf16 fragment
__device__ __forceinline__ v8s ldf8(const float* p) {
  float4 a = *(const float4*)p;
  float4 b = *(const float4*)(p + 4);
  union { v8s v; unsigned short u[8]; } r;
  r.u[0] = f2b(a.x); r.u[1] = f2b(a.y); r.u[2] = f2b(a.z); r.u[3] = f2b(a.w);
  r.u[4] = f2b(b.x); r.u[5] = f2b(b.y); r.u[6] = f2b(b.z); r.u[7] = f2b(b.w);
  return r.v;
}
// load 16 bytes (8 bf16) via two 8B LDS reads (rows may be only 8B-aligned)
__device__ __forceinline__ v8s ld16u(const unsigned short* p) {
  union { v8s v; ushort4 h[2]; } u;
  u.h[0] = *(const ushort4*)(p);
  u.h[1] = *(const ushort4*)(p + 4);
  return u.v;
}

#define SCALE 0.17677669529663687f
#define LOG2E 1.4426950408889634f
#define QSCALE (SCALE * LOG2E)   // fold base-2 exp into Q scaling

// workspace layout (bytes):
//   [0, 16 MiB)                  msum[256][128][128]  fp32 ((mask+sp)*log2e, [n][m])
//   [16 MiB, +256 KiB)           rpb[4][128][128]     fp32 (btab[rpi]*log2e, [n][m])
//   [17039360, +96 KiB)          wqh: w_qkv bf16 row-major 384x128
//   [17137664, +32 KiB)          wph: w_proj bf16 row-major 128x128
#define WS_RPB 16777216
#define WS_WQH 17039360
#define WS_WPH 17137664

// ---------------- K0a: weight fp32 -> bf16 (65536 elems, grid 256) ----------
__global__ __launch_bounds__(256)
void conv_w(const float* __restrict__ wq, const float* __restrict__ wp,
            unsigned short* __restrict__ wqh, unsigned short* __restrict__ wph) {
  int i = blockIdx.x * 256 + threadIdx.x;
  if (i < 384 * 128) wqh[i] = f2b(wq[i]);
  else wph[i - 384 * 128] = f2b(wp[i - 384 * 128]);
}

// ---------------- K0b: bias precompute (grid 256 = wgrp) --------------------
// msum[wgrp][n][m] = (mask[wgrp][n][m] + sp[wgrp][n][m]) * log2e  (no transpose)
// rpb flat e = h*16384 + n*128 + m = btab[rpi[n][m]*4 + h] * log2e
__global__ __launch_bounds__(256)
void build_bias(const float* __restrict__ mask, const float* __restrict__ sp,
                const int* __restrict__ rpi, const float* __restrict__ btab,
                float* __restrict__ msum, float* __restrict__ rpb) {
  const int wgrp = blockIdx.x, tid = threadIdx.x;
  const float* mk = mask + (size_t)wgrp * 16384;
  const float* sk = sp + (size_t)wgrp * 16384;
  float* ot = msum + (size_t)wgrp * 16384;
  for (int it = 0; it < 16; ++it) {
    int i = (tid + 256 * it) * 4;
    float4 a = *(const float4*)(mk + i);
    float4 b = *(const float4*)(sk + i);
    float4 s;
    s.x = (a.x + b.x) * LOG2E; s.y = (a.y + b.y) * LOG2E;
    s.z = (a.z + b.z) * LOG2E; s.w = (a.w + b.w) * LOG2E;
    *(float4*)(ot + i) = s;
  }
  int e = wgrp * 256 + tid;            // 0..65535 over [h][n][m]
  int hh = e >> 14, r = e & 16383;
  rpb[e] = btab[rpi[r] * 4 + hh] * LOG2E;
}

// ---------------- K1: fused qkv + attention per (b, h) ----------------
// No X staging (wave-local fragments load direct from global), no P buffer
// (S computed transposed -> in-register shuffle redistribution), ONE barrier.
// LDS = 17664 B -> occupancy VGPR-bound (~4-5 blocks/CU).
__global__ __launch_bounds__(256, 4)
void attn_kernel(const float* __restrict__ xg,
                 const unsigned short* __restrict__ wqh,
                 const float* __restrict__ bq,
                 const float* __restrict__ msum,
                 const float* __restrict__ rpb,
                 float* __restrict__ o_ws) {
  // LDS: [0,9216) K (128x36 bf16)   [9216,17664) V^T (32x132 bf16)
  __shared__ alignas(16) unsigned char smem[17664];
  unsigned short* kss = (unsigned short*)smem;
  unsigned short* vs  = (unsigned short*)(smem + 9216);

  const int tid = threadIdx.x;
  const int wv = tid >> 6;
  const int lane = tid & 63;
  const int qd = lane >> 4;   // quarter 0..3
  const int t16 = lane & 15;

  const int idx = blockIdx.x;
  const int wgrp = idx >> 5;          // 0..255 : mask index
  const int rem = idx & 31;
  const int h = rem >> 3;             // head
  const int b = (rem & 7) * 256 + wgrp;  // window (b % 256 == wgrp)

  // ---- phase 1: X fragments direct from global (wave-local 32-token strip) ----
  const float* xb = xg + (size_t)b * 16384;
  v8s bx[2][4];
  for (int nt = 0; nt < 2; ++nt)
    for (int ks = 0; ks < 4; ++ks) {
      int n = 32 * wv + nt * 16 + t16;
      bx[nt][ks] = ldf8(xb + n * 128 + ks * 32 + 8 * qd);
    }

  // q,k via out^T = W @ X^T : rows j (0..63: q then k), cols n (wave strip 32)
  v4f accqk[4][2];
  for (int jt = 0; jt < 4; ++jt)
    for (int nt = 0; nt < 2; ++nt) accqk[jt][nt] = v4f{0.f, 0.f, 0.f, 0.f};
  for (int jt = 0; jt < 4; ++jt) {
    int wbase = (jt < 2) ? (h * 32 + jt * 16) : (128 + h * 32 + (jt - 2) * 16);
    for (int ks = 0; ks < 4; ++ks) {
      v8s a = *(const v8s*)(wqh + (wbase + t16) * 128 + ks * 32 + 8 * qd);
      for (int nt = 0; nt < 2; ++nt)
        accqk[jt][nt] = MFMA16(a, bx[nt][ks], accqk[jt][nt]);
    }
  }
  // v via out = X @ Wv^T : rows n (strip 32), cols d (32)
  v4f accv[2][2];
  for (int rt = 0; rt < 2; ++rt)
    for (int ct = 0; ct < 2; ++ct) accv[rt][ct] = v4f{0.f, 0.f, 0.f, 0.f};
  for (int ct = 0; ct < 2; ++ct)
    for (int ks = 0; ks < 4; ++ks) {
      v8s bw = *(const v8s*)(wqh + (256 + h * 32 + ct * 16 + t16) * 128 + ks * 32 + 8 * qd);
      for (int rt = 0; rt < 2; ++rt)
        accv[rt][ct] = MFMA16(bx[rt][ks], bw, accv[rt][ct]);
    }

  // epilogue k (jt=2,3): packed 8B LDS stores to K[token][d]
  for (int jt = 2; jt < 4; ++jt)
    for (int nt = 0; nt < 2; ++nt) {
      int n = 32 * wv + nt * 16 + t16;
      ushort4 pk;
      float v0 = accqk[jt][nt][0] + bq[128 + h * 32 + (jt - 2) * 16 + 4 * qd + 0];
      float v1 = accqk[jt][nt][1] + bq[128 + h * 32 + (jt - 2) * 16 + 4 * qd + 1];
      float v2 = accqk[jt][nt][2] + bq[128 + h * 32 + (jt - 2) * 16 + 4 * qd + 2];
      float v3 = accqk[jt][nt][3] + bq[128 + h * 32 + (jt - 2) * 16 + 4 * qd + 3];
      pk.x = f2b(v0); pk.y = f2b(v1); pk.z = f2b(v2); pk.w = f2b(v3);
      *(ushort4*)(kss + n * 36 + (jt - 2) * 16 + 4 * qd) = pk;
    }
  // epilogue v: store transposed V^T[d][n], 4 consecutive n per reg -> 8B stores
  for (int ct = 0; ct < 2; ++ct) {
    int d = ct * 16 + t16;
    float bv = bq[256 + h * 32 + d];
    for (int rt = 0; rt < 2; ++rt) {
      ushort4 pk;
      pk.x = f2b(accv[rt][ct][0] + bv);
      pk.y = f2b(accv[rt][ct][1] + bv);
      pk.z = f2b(accv[rt][ct][2] + bv);
      pk.w = f2b(accv[rt][ct][3] + bv);
      *(ushort4*)(vs + d * 132 + 32 * wv + rt * 16 + 4 * qd) = pk;
    }
  }

  // ---- Q: pack bf16 dword pairs, redistribute in-register (no LDS) ----
  // target (qd,t16) needs aq[rt] = Q[n = 32wv+rt*16+t16][8qd..8qd+7]
  unsigned int qpk[2][2][2];  // [jt][nt][dw]
  for (int jt = 0; jt < 2; ++jt)
    for (int nt = 0; nt < 2; ++nt) {
      float vv[4];
      for (int r = 0; r < 4; ++r)
        vv[r] = (accqk[jt][nt][r] + bq[h * 32 + jt * 16 + 4 * qd + r]) * QSCALE;
      qpk[jt][nt][0] = (unsigned int)f2b(vv[0]) | ((unsigned int)f2b(vv[1]) << 16);
      qpk[jt][nt][1] = (unsigned int)f2b(vv[2]) | ((unsigned int)f2b(vv[3]) << 16);
    }
  const int srcA = ((qd & 1) << 5) + t16;
  const bool hiq = qd >= 2;
  v8s aq[2];
  for (int rt = 0; rt < 2; ++rt) {
    union { v8s v; unsigned int d[4]; } u;
    unsigned int a0 = __shfl((int)qpk[0][rt][0], srcA, 64);
    unsigned int b0 = __shfl((int)qpk[1][rt][0], srcA, 64);
    unsigned int a1 = __shfl((int)qpk[0][rt][1], srcA, 64);
    unsigned int b1 = __shfl((int)qpk[1][rt][1], srcA, 64);
    unsigned int a2 = __shfl((int)qpk[0][rt][0], srcA + 16, 64);
    unsigned int b2 = __shfl((int)qpk[1][rt][0], srcA + 16, 64);
    unsigned int a3 = __shfl((int)qpk[0][rt][1], srcA + 16, 64);
    unsigned int b3 = __shfl((int)qpk[1][rt][1], srcA + 16, 64);
    u.d[0] = hiq ? b0 : a0;
    u.d[1] = hiq ? b1 : a1;
    u.d[2] = hiq ? b2 : a2;
    u.d[3] = hiq ? b3 : a3;
    aq[rt] = u.v;
  }
  __syncthreads();   // the ONLY barrier: K,V visible to all waves

  // ---- phase 2: S^T = K Q^T (+ bias), softmax over m (rows), all in-lane ----
  // C layout: row-quad = m = ct*16+4qd+r ; col = n = 32wv+nt*16+t16
  v4f sa[2][8];   // [nt][ct]
  const v4f zero4 = {0.f, 0.f, 0.f, 0.f};
  for (int ct = 0; ct < 8; ++ct) {
    v8s bk = ld16u(kss + (ct * 16 + t16) * 36 + 8 * qd);
    for (int nt = 0; nt < 2; ++nt)
      sa[nt][ct] = MFMA16(bk, aq[nt], zero4);
  }
  // bias: msum[wgrp][n][m] + rpb[h][n][m], float4 along m (matches quad)
  {
    const float* mt = msum + (size_t)wgrp * 16384;
    const float* rb = rpb + (size_t)h * 16384;
    for (int nt = 0; nt < 2; ++nt) {
      int n = 32 * wv + nt * 16 + t16;
      const float* pm = mt + n * 128;
      const float* pr = rb + n * 128;
      for (int ct = 0; ct < 8; ++ct) {
        float4 b1 = *(const float4*)(pm + ct * 16 + 4 * qd);
        float4 b2 = *(const float4*)(pr + ct * 16 + 4 * qd);
        sa[nt][ct][0] += b1.x + b2.x;
        sa[nt][ct][1] += b1.y + b2.y;
        sa[nt][ct][2] += b1.z + b2.z;
        sa[nt][ct][3] += b1.w + b2.w;
      }
    }
  }
  // softmax denominators per column n: 32 in-lane + shfl_xor over qd bits
  float pinv[2];
  for (int nt = 0; nt < 2; ++nt) {
    float m0 = sa[nt][0][0];
    for (int ct = 0; ct < 8; ++ct)
      for (int r = 0; r < 4; ++r) m0 = fmaxf(m0, sa[nt][ct][r]);
    m0 = fmaxf(m0, __shfl_xor(m0, 16));
    m0 = fmaxf(m0, __shfl_xor(m0, 32));
    for (int ct = 0; ct < 8; ++ct)
      for (int r = 0; r < 4; ++r)
        sa[nt][ct][r] = exp2f(sa[nt][ct][r] - m0);
    float s0 = 0.f;
    for (int ct = 0; ct < 8; ++ct)
      for (int r = 0; r < 4; ++r) s0 += sa[nt][ct][r];
    s0 += __shfl_xor(s0, 16);
    s0 += __shfl_xor(s0, 32);
    pinv[nt] = 1.0f / s0;
  }

  // ---- phase 3: per n-tile: pack P, shuffle to A-frag layout, PV MFMA ----
  v8s av[2][4];
  for (int rt = 0; rt < 2; ++rt)
    for (int ks = 0; ks < 4; ++ks)
      av[rt][ks] = ld16u(vs + (rt * 16 + t16) * 132 + ks * 32 + 8 * qd);

  const int srcP0 = ((qd & 1) << 5) + t16;   // lane holding m-quads 8(qd&1)+{0..3}
  const bool hip2 = qd >= 2;                 // selects register 2ks vs 2ks+1
  for (int nt = 0; nt < 2; ++nt) {
    // pack unnormalized P (values in (0,1]) to bf16 dword pairs
    unsigned int pkd[8][2];
    for (int ct = 0; ct < 8; ++ct) {
      pkd[ct][0] = (unsigned int)f2b(sa[nt][ct][0]) | ((unsigned int)f2b(sa[nt][ct][1]) << 16);
      pkd[ct][1] = (unsigned int)f2b(sa[nt][ct][2]) | ((unsigned int)f2b(sa[nt][ct][3]) << 16);
    }
    // redistribute: target (qd,t16) gets P[n][m = ks*32+8qd .. +7]
    v8s bp[4];
    for (int ks = 0; ks < 4; ++ks) {
      union { v8s v; unsigned int d[4]; } u;
      unsigned int a0 = __shfl((int)pkd[2 * ks][0], srcP0, 64);
      unsigned int b0 = __shfl((int)pkd[2 * ks + 1][0], srcP0, 64);
      unsigned int a1 = __shfl((int)pkd[2 * ks][1], srcP0, 64);
      unsigned int b1 = __shfl((int)pkd[2 * ks + 1][1], srcP0, 64);
      unsigned int a2 = __shfl((int)pkd[2 * ks][0], srcP0 + 16, 64);
      unsigned int b2 = __shfl((int)pkd[2 * ks + 1][0], srcP0 + 16, 64);
      unsigned int a3 = __shfl((int)pkd[2 * ks][1], srcP0 + 16, 64);
      unsigned int b3 = __shfl((int)pkd[2 * ks + 1][1], srcP0 + 16, 64);
      u.d[0] = hip2 ? b0 : a0;
      u.d[1] = hip2 ? b1 : a1;
      u.d[2] = hip2 ? b2 : a2;
      u.d[3] = hip2 ? b3 : a3;
      bp[ks] = u.v;
    }
    // O^T[d][n] = V^T P^T for this n-tile; scale by pinv[nt] at the end
    v4f oa[2] = {zero4, zero4};
    for (int ks = 0; ks < 4; ++ks)
      for (int rt = 0; rt < 2; ++rt)
        oa[rt] = MFMA16(av[rt][ks], bp[ks], oa[rt]);
    int n = 32 * wv + nt * 16 + t16;
    float s = pinv[nt];
    for (int rt = 0; rt < 2; ++rt) {
      int cbase = h * 32 + rt * 16 + 4 * qd;
      float4 pk;
      pk.x = oa[rt][0] * s;
      pk.y = oa[rt][1] * s;
      pk.z = oa[rt][2] * s;
      pk.w = oa[rt][3] * s;
      *(float4*)(o_ws + ((size_t)(b * 128 + n)) * 128 + cbase) = pk;
    }
  }
}

// ---------------- K2: out = O @ w_proj^T + b_proj (IN PLACE on d_out) -------
// No LDS, no barrier: wave-local row strips, loads retire before stores
// (stores depend on MFMA results -> vmcnt waits cover all fragment loads).
__global__ __launch_bounds__(256, 4)
void proj_kernel(const unsigned short* __restrict__ wph,
                 const float* __restrict__ bpj,
                 float* __restrict__ out) {
  const int tid = threadIdx.x;
  const int wv = tid >> 6;
  const int lane = tid & 63;
  const int qd = lane >> 4;
  const int t16 = lane & 15;
  const size_t row0 = (size_t)blockIdx.x * 128;
  const float* src = out + row0 * 128;

  // B-frags: token rows n direct from global (wave-local strip)
  v8s bo[2][4];
  for (int ct = 0; ct < 2; ++ct)
    for (int ks = 0; ks < 4; ++ks) {
      int n = 32 * wv + ct * 16 + t16;
      bo[ct][ks] = ldf8(src + n * 128 + ks * 32 + 8 * qd);
    }
  v4f acc[8][2];
  for (int rt = 0; rt < 8; ++rt)
    for (int ct = 0; ct < 2; ++ct) acc[rt][ct] = v4f{0.f, 0.f, 0.f, 0.f};
  for (int rt = 0; rt < 8; ++rt)
    for (int ks = 0; ks < 4; ++ks) {
      v8s a = *(const v8s*)(wph + (rt * 16 + t16) * 128 + ks * 32 + 8 * qd);
      for (int ct = 0; ct < 2; ++ct)
        acc[rt][ct] = MFMA16(a, bo[ct][ks], acc[rt][ct]);
    }
  for (int rt = 0; rt < 8; ++rt) {
    float4 bj = *(const float4*)(bpj + rt * 16 + 4 * qd);
    for (int ct = 0; ct < 2; ++ct) {
      int n = 32 * wv + ct * 16 + t16;
      float4 pk;
      pk.x = acc[rt][ct][0] + bj.x;
      pk.y = acc[rt][ct][1] + bj.y;
      pk.z = acc[rt][ct][2] + bj.z;
      pk.w = acc[rt][ct][3] + bj.w;
      *(float4*)(out + (row0 + n) * 128 + rt * 16 + 4 * qd) = pk;
    }
  }
}

// ---------------- launch ----------------
extern "C" void kernel_launch(void* const* d_in, const int* in_sizes, int n_in,
                              void* d_out, int out_size, void* d_ws, size_t ws_size,
                              hipStream_t stream) {
  (void)in_sizes; (void)n_in; (void)out_size; (void)ws_size;
  const float* xg   = (const float*)d_in[0];
  const int*   rpi  = (const int*)d_in[1];
  const float* mask = (const float*)d_in[2];
  const float* sp   = (const float*)d_in[3];
  const float* wq   = (const float*)d_in[4];
  const float* bq   = (const float*)d_in[5];
  const float* btab = (const float*)d_in[6];
  const float* wp   = (const float*)d_in[7];
  const float* bpj  = (const float*)d_in[8];
  float* out = (float*)d_out;

  float* msum = (float*)d_ws;                                    // 16 MiB
  float* rpb  = (float*)((char*)d_ws + WS_RPB);                  // 256 KiB
  unsigned short* wqh = (unsigned short*)((char*)d_ws + WS_WQH); // 96 KiB
  unsigned short* wph = (unsigned short*)((char*)d_ws + WS_WPH); // 32 KiB

  conv_w<<<256, 256, 0, stream>>>(wq, wp, wqh, wph);
  build_bias<<<256, 256, 0, stream>>>(mask, sp, rpi, btab, msum, rpb);
  // O intermediate lives in d_out; proj projects in place.
  attn_kernel<<<8192, 256, 0, stream>>>(xg, wqh, bq, msum, rpb, out);
  proj_kernel<<<2048, 256, 0, stream>>>(wph, bpj, out);
}